// Round 1
// baseline (26.255 us; speedup 1.0000x reference)
//
#include <hip/hip_runtime.h>
#include <math.h>

#define Bn 16
#define Cn 10
#define Hn 400
#define Wn 352
#define Nn 50
#define PLANE (Hn * Wn)          // 140800
#define NCHUNK 32
#define CHUNK ((PLANE + NCHUNK - 1) / NCHUNK)   // 4400
#define BKG_THRESH 0.025f
#define LOG_CLAMP -100.0f

// stable log(1+exp(x))
__device__ __forceinline__ float softplusf(float x) {
    return fmaxf(x, 0.0f) + log1pf(expf(-fabsf(x)));
}

__device__ __forceinline__ float sigmoidf(float x) {
    return 1.0f / (1.0f + expf(-x));
}

// ---------------- kernel 1: per-(sample,chunk) plane reductions -------------
// partials[(b*NCHUNK + ch)*3 + {0:sum_sigmoid, 1:sum_logv_sel, 2:count_sel}]
__global__ void plane_reduce(const float* __restrict__ out, float* __restrict__ partials) {
    const int b  = blockIdx.x / NCHUNK;
    const int ch = blockIdx.x % NCHUNK;
    const float* plane = out + (size_t)b * Cn * PLANE;  // channel 0 of sample b
    const int start = ch * CHUNK;
    const int end   = min(start + CHUNK, PLANE);

    float s_sig = 0.0f, s_log = 0.0f, s_cnt = 0.0f;
    for (int i = start + threadIdx.x; i < end; i += blockDim.x) {
        float x = plane[i];
        float p = sigmoidf(x);
        s_sig += p;
        if (p > BKG_THRESH) {
            s_cnt += 1.0f;
            // logv = max(log_sigmoid(-x), -100) = max(-softplus(x), -100)
            s_log += fmaxf(-softplusf(x), LOG_CLAMP);
        }
    }

    __shared__ float sh0[256], sh1[256], sh2[256];
    const int tid = threadIdx.x;
    sh0[tid] = s_sig; sh1[tid] = s_log; sh2[tid] = s_cnt;
    __syncthreads();
    for (int off = 128; off > 0; off >>= 1) {
        if (tid < off) {
            sh0[tid] += sh0[tid + off];
            sh1[tid] += sh1[tid + off];
            sh2[tid] += sh2[tid + off];
        }
        __syncthreads();
    }
    if (tid == 0) {
        float* p = partials + (size_t)(b * NCHUNK + ch) * 3;
        p[0] = sh0[0]; p[1] = sh1[0]; p[2] = sh2[0];
    }
}

__device__ __forceinline__ float wave_sum(float v) {
    for (int off = 32; off > 0; off >>= 1) v += __shfl_down(v, off);
    return __shfl(v, 0);
}

// ---------------- kernel 2: per-sample loss terms ----------------------------
// terms[b*6 + j]
__global__ void sample_loss(const float* __restrict__ out,
                            const float* __restrict__ tgt,
                            const float* __restrict__ partials,
                            float* __restrict__ terms) {
    const int b = blockIdx.x;
    const int lane = threadIdx.x;   // 0..63, one wave

    // ---- reduce plane partials (32 chunks) ----
    float s_sig = 0.0f, s_log = 0.0f, s_cnt = 0.0f;
    if (lane < NCHUNK) {
        const float* p = partials + (size_t)(b * NCHUNK + lane) * 3;
        s_sig = p[0]; s_log = p[1]; s_cnt = p[2];
    }
    s_sig = wave_sum(s_sig);
    s_log = wave_sum(s_log);
    s_cnt = wave_sum(s_cnt);

    // ---- load the 50 targets, one per lane ----
    const float* t = tgt + (size_t)b * Nn * 7;
    const bool active = lane < Nn;
    float tx = 0.0f, ty = 0.0f, t2 = 0.0f, t3 = 1.0f, t4 = 1.0f, t5 = 1.0f, ang = 0.0f;
    int key = -1;
    __shared__ int keys[Nn];
    if (active) {
        tx = t[lane * 7 + 0] * 2.0f;
        ty = t[lane * 7 + 1] * 2.0f;
        t2 = t[lane * 7 + 2];
        t3 = t[lane * 7 + 3];
        t4 = t[lane * 7 + 4];
        t5 = t[lane * 7 + 5];
        ang = t[lane * 7 + 6];
        int dx = (int)floorf(tx);
        int dy = (int)floorf(ty);
        key = dx * Wn + dy;
        keys[lane] = key;
    }
    __syncthreads();

    // first-occurrence dedupe (mask semantics: each unique cell masked once)
    bool isfirst = active;
    if (active) {
        for (int m = 0; m < lane; ++m) {
            if (keys[m] == key) { isfirst = false; break; }
        }
    }

    // ---- gather the 10 channels at the point ----
    const float* base = out + (size_t)b * Cn * PLANE;
    float g[10];
    if (active) {
        #pragma unroll
        for (int c = 0; c < 10; ++c) g[c] = base[(size_t)c * PLANE + key];
    } else {
        #pragma unroll
        for (int c = 0; c < 10; ++c) g[c] = 0.0f;
    }

    // ---- corrections for masked (unique) points ----
    float c_sig = 0.0f, c_log = 0.0f, c_cnt = 0.0f, c_n = 0.0f;
    if (isfirst) {
        float p = sigmoidf(g[0]);
        c_sig = p;
        c_n = 1.0f;
        if (p > BKG_THRESH) {
            c_cnt = 1.0f;
            c_log = fmaxf(-softplusf(g[0]), LOG_CLAMP);
        }
    }
    c_sig = wave_sum(c_sig);
    c_log = wave_sum(c_log);
    c_cnt = wave_sum(c_cnt);
    c_n   = wave_sum(c_n);

    // ---- per-point loss contributions (ALL 50 points, duplicates included) ----
    float v_obj = 0.0f, v_xyz = 0.0f, v_hwl = 0.0f, v_acl = 0.0f, v_asin = 0.0f;
    if (active) {
        // objcls: -max(log_sigmoid(g0), -100); log_sigmoid(x) = -softplus(-x)
        v_obj = -fmaxf(-softplusf(-g[0]), LOG_CLAMP);

        float fx = tx - floorf(tx);
        float fy = ty - floorf(ty);
        float tz = t2 * 0.25f;                 // ZSIZE = 4.0
        float e0 = sigmoidf(g[1]) - fx;
        float e1 = sigmoidf(g[2]) - fy;
        float e2 = sigmoidf(g[3]) - tz;
        v_xyz = e0 * e0 + e1 * e1 + e2 * e2;

        float h0 = g[4] - logf(t3 / 1.52f);
        float h1 = g[5] - logf(t4 / 1.63f);
        float h2 = g[6] - logf(t5 / 3.88f);
        v_hwl = h0 * h0 + h1 * h1 + h2 * h2;

        // anglecls: -log_softmax([g7,g8])[cls], cls = (ang >= 0)
        float m = fmaxf(g[7], g[8]);
        float lse = m + logf(expf(g[7] - m) + expf(g[8] - m));
        float gsel = (ang >= 0.0f) ? g[8] : g[7];
        v_acl = lse - gsel;

        float d = sinf(g[9]) - sinf(sinf(ang));
        float ad = fabsf(d);
        v_asin = (ad < 1.0f) ? 0.5f * d * d : ad - 0.5f;
    }
    v_obj  = wave_sum(v_obj);
    v_xyz  = wave_sum(v_xyz);
    v_hwl  = wave_sum(v_hwl);
    v_acl  = wave_sum(v_acl);
    v_asin = wave_sum(v_asin);

    if (lane == 0) {
        float nbkg    = (float)PLANE - c_n;
        float sig_bkg = s_sig - c_sig;
        float clsscale = expf(-3.0f * sig_bkg / nbkg) * 2.5f;

        float cnt  = s_cnt - c_cnt;
        float slog = s_log - c_log;
        float bkg_l = (cnt > 0.0f) ? (-slog / fmaxf(cnt, 1.0f)) : 0.0f;

        const float invN  = 1.0f / (float)Nn;
        const float invN3 = 1.0f / (float)(Nn * 3);

        float* o = terms + (size_t)b * 6;
        o[0] = bkg_l;
        o[1] = v_obj * invN * clsscale;
        o[2] = v_xyz * invN3;
        o[3] = v_hwl * invN3 * 0.5f;
        o[4] = v_acl * invN * 0.5f;
        o[5] = v_asin * invN * 0.5f;
    }
}

// ---------------- kernel 3: final reduce over batch -------------------------
__global__ void finalize(const float* __restrict__ terms, float* __restrict__ out7) {
    if (threadIdx.x == 0 && blockIdx.x == 0) {
        float s[6] = {0, 0, 0, 0, 0, 0};
        for (int b = 0; b < Bn; ++b)
            for (int j = 0; j < 6; ++j)
                s[j] += terms[b * 6 + j];
        float tot = 0.0f;
        for (int j = 0; j < 6; ++j) tot += s[j];
        out7[0] = tot;
        for (int j = 0; j < 6; ++j) out7[1 + j] = s[j];
    }
}

extern "C" void kernel_launch(void* const* d_in, const int* in_sizes, int n_in,
                              void* d_out, int out_size, void* d_ws, size_t ws_size,
                              hipStream_t stream) {
    const float* out = (const float*)d_in[0];   // (B, C, H, W) f32
    const float* tgt = (const float*)d_in[1];   // (B, N, 7)   f32
    float* o  = (float*)d_out;                  // 7 floats
    float* ws = (float*)d_ws;

    float* partials = ws;          // Bn*NCHUNK*3 = 1536 floats
    float* terms    = ws + 2048;   // Bn*6 = 96 floats

    plane_reduce<<<Bn * NCHUNK, 256, 0, stream>>>(out, partials);
    sample_loss<<<Bn, 64, 0, stream>>>(out, tgt, partials, terms);
    finalize<<<1, 64, 0, stream>>>(terms, o);
}